// Round 11
// baseline (48.253 us; speedup 1.0000x reference)
//
#include <hip/hip_runtime.h>
#include <math.h>

#define BSZ 4
#define LEN_M 256
#define LEN_E 512
#define HDIM 512
#define KDIM 512
#define VOCAB 32000
#define CHUNK 4000     // 16 KB LDS -> 8 blocks/CU (thread-capped), full occupancy

typedef __attribute__((ext_vector_type(8))) short bf16x8;
typedef __attribute__((ext_vector_type(4))) float f32x4;

__device__ inline ushort f2bf(float x) {
    union { float f; unsigned u; } v; v.f = x;
    unsigned r = v.u + 0x7FFFu + ((v.u >> 16) & 1u);   // RNE
    return (ushort)(r >> 16);
}

// ---- bf16 A[M][K] @ B[N][K]^T core: 64x64 tile, 4 waves, 16x16x32 MFMA -------
// LROW=72: 16B-aligned b128 ops, lanes spread across disjoint 4-bank groups.
// LDS DOUBLE-BUFFERED: write tile kt+1 while computing kt -> 1 barrier/K-tile
// (was 2). Safe: iter kt writes buf (kt+1)&1, which all threads finished
// reading before the barrier that ended iter kt-1.
#define LROW 72
#define TILE_E (64 * LROW)
template<bool OUT_BF16>
__device__ __forceinline__ void gemm_core(const ushort* __restrict__ Ab,
                                          const ushort* __restrict__ Bb,
                                          void* __restrict__ Cb, int N, float scale,
                                          ushort* As, ushort* Bs, int m0, int n0) {
    const int t = threadIdx.x;
    const int wid = t >> 6, lane = t & 63;
    const int wr = wid >> 1, wc = wid & 1;
    const int lrow = lane & 15, lk = (lane >> 4) * 8;
    const int r0 = t >> 3;
    const int c8 = (t & 7) * 8;

    bf16x8 pa0, pa1, pb0, pb1;
    f32x4 acc[2][2] = {};

    // stage K-tile 0 into buffer 0
    pa0 = *(const bf16x8*)&Ab[(size_t)(m0 + r0)      * KDIM + c8];
    pa1 = *(const bf16x8*)&Ab[(size_t)(m0 + r0 + 32) * KDIM + c8];
    pb0 = *(const bf16x8*)&Bb[(size_t)(n0 + r0)      * KDIM + c8];
    pb1 = *(const bf16x8*)&Bb[(size_t)(n0 + r0 + 32) * KDIM + c8];
    *(bf16x8*)&As[(r0)      * LROW + c8] = pa0;
    *(bf16x8*)&As[(r0 + 32) * LROW + c8] = pa1;
    *(bf16x8*)&Bs[(r0)      * LROW + c8] = pb0;
    *(bf16x8*)&Bs[(r0 + 32) * LROW + c8] = pb1;
    __syncthreads();

    for (int kt = 0; kt < KDIM / 64; ++kt) {
        ushort* Ac = As + (kt & 1) * TILE_E;
        ushort* Bc = Bs + (kt & 1) * TILE_E;
        const bool more = (kt + 1 < KDIM / 64);
        if (more) {                          // prefetch next K-tile into regs
            const int k0 = (kt + 1) * 64;
            pa0 = *(const bf16x8*)&Ab[(size_t)(m0 + r0)      * KDIM + k0 + c8];
            pa1 = *(const bf16x8*)&Ab[(size_t)(m0 + r0 + 32) * KDIM + k0 + c8];
            pb0 = *(const bf16x8*)&Bb[(size_t)(n0 + r0)      * KDIM + k0 + c8];
            pb1 = *(const bf16x8*)&Bb[(size_t)(n0 + r0 + 32) * KDIM + k0 + c8];
        }
#pragma unroll
        for (int ks = 0; ks < 2; ++ks) {
            bf16x8 af[2], bfr[2];
#pragma unroll
            for (int i = 0; i < 2; ++i)
                af[i]  = *(const bf16x8*)&Ac[(wr * 32 + i * 16 + lrow) * LROW + ks * 32 + lk];
#pragma unroll
            for (int j = 0; j < 2; ++j)
                bfr[j] = *(const bf16x8*)&Bc[(wc * 32 + j * 16 + lrow) * LROW + ks * 32 + lk];
#pragma unroll
            for (int i = 0; i < 2; ++i)
#pragma unroll
                for (int j = 0; j < 2; ++j)
                    acc[i][j] = __builtin_amdgcn_mfma_f32_16x16x32_bf16(af[i], bfr[j], acc[i][j], 0, 0, 0);
        }
        if (more) {                          // write next tile to OTHER buffer
            ushort* An = As + ((kt + 1) & 1) * TILE_E;
            ushort* Bn = Bs + ((kt + 1) & 1) * TILE_E;
            *(bf16x8*)&An[(r0)      * LROW + c8] = pa0;
            *(bf16x8*)&An[(r0 + 32) * LROW + c8] = pa1;
            *(bf16x8*)&Bn[(r0)      * LROW + c8] = pb0;
            *(bf16x8*)&Bn[(r0 + 32) * LROW + c8] = pb1;
            __syncthreads();                 // single barrier per K-tile
        }
    }

    // C/D layout (m89): col = lane&15, row = (lane>>4)*4 + reg
    const int crow = m0 + wr * 32 + (lane >> 4) * 4;
    const int ccol = n0 + wc * 32 + lrow;
#pragma unroll
    for (int i = 0; i < 2; ++i)
#pragma unroll
        for (int j = 0; j < 2; ++j)
#pragma unroll
            for (int r = 0; r < 4; ++r) {
                const size_t o = (size_t)(crow + i * 16 + r) * N + ccol + j * 16;
                const float v = acc[i][j][r] * scale;
                if (OUT_BF16) ((ushort*)Cb)[o] = f2bf(v);
                else          ((float*)Cb)[o]  = v;
            }
}

// ---- convert M,E -> bf16; We,Wm -> bf16 transposed; lambda per row -----------
// blocks 0..1535: elementwise | 1536..1663: transposes | 1664..1919: lambda
__global__ __launch_bounds__(256) void convert_tr(const float* __restrict__ M_,
                                                  const float* __restrict__ E_,
                                                  const float* __restrict__ We_,
                                                  const float* __restrict__ Wm_,
                                                  const float* __restrict__ D,
                                                  const float* __restrict__ Cq,
                                                  const float* __restrict__ Cc,
                                                  const float* __restrict__ Wl,
                                                  const float* __restrict__ bl,
                                                  ushort* __restrict__ Mbf,
                                                  ushort* __restrict__ Ebf,
                                                  ushort* __restrict__ WeT,
                                                  ushort* __restrict__ WmT,
                                                  float* __restrict__ lam) {
    __shared__ ushort Ts[64][68];
    const int blk = blockIdx.x;
    if (blk < 1536) {
        const int i4 = blk * 256 + threadIdx.x;
        const float* src; ushort* dst; int off;
        if (i4 < 131072) { src = M_; dst = Mbf; off = 0; }
        else             { src = E_; dst = Ebf; off = 131072; }
        const int j = i4 - off;
        const float4 v = ((const float4*)src)[j];
        ushort4 o; o.x = f2bf(v.x); o.y = f2bf(v.y); o.z = f2bf(v.z); o.w = f2bf(v.w);
        ((ushort4*)dst)[j] = o;
    } else if (blk < 1664) {
        const int ti  = blk - 1536;
        const int mat = ti >> 6;
        const int tt  = ti & 63;
        const int kt  = tt >> 3, nt = tt & 7;
        const float* W = mat ? Wm_ : We_;
        ushort* WT     = mat ? WmT : WeT;
        const int r = threadIdx.x >> 4, c4 = (threadIdx.x & 15) * 4;
#pragma unroll
        for (int p = 0; p < 4; ++p) {
            const int row = r + p * 16;
            const float4 v = *(const float4*)&W[(size_t)(kt * 64 + row) * HDIM + nt * 64 + c4];
            Ts[row][c4 + 0] = f2bf(v.x); Ts[row][c4 + 1] = f2bf(v.y);
            Ts[row][c4 + 2] = f2bf(v.z); Ts[row][c4 + 3] = f2bf(v.w);
        }
        __syncthreads();
#pragma unroll
        for (int p = 0; p < 4; ++p) {
            const int row = r + p * 16;
            ushort4 o;
            o.x = Ts[c4 + 0][row]; o.y = Ts[c4 + 1][row];
            o.z = Ts[c4 + 2][row]; o.w = Ts[c4 + 3][row];
            *(ushort4*)&WT[(size_t)(nt * 64 + row) * HDIM + kt * 64 + c4] = o;
        }
    } else {
        // lambda: one wave per row, 4 rows per block
        const int lane = threadIdx.x & 63, wv = threadIdx.x >> 6;
        const int bm = (blk - 1664) * 4 + wv;          // 0..1023
        const size_t rb = (size_t)bm * HDIM;
        float s = 0.f;
#pragma unroll
        for (int h = 0; h < HDIM; h += 64) {
            const int e = h + lane;
            s += D[rb + e] * Wl[e] + Cq[rb + e] * Wl[HDIM + e] + Cc[rb + e] * Wl[2 * HDIM + e];
        }
#pragma unroll
        for (int o = 32; o; o >>= 1) s += __shfl_xor(s, o);
        if (lane == 0) lam[bm] = 1.f / (1.f + expf(-(s + bl[0])));
    }
}

// ---- Ep = E @ We and Mp = s * (M @ Wm) in ONE launch --------------------------
__global__ __launch_bounds__(256) void gemm_epmp(const ushort* __restrict__ Ebf,
                                                 const ushort* __restrict__ Mbf,
                                                 const ushort* __restrict__ WeT,
                                                 const ushort* __restrict__ WmT,
                                                 ushort* __restrict__ Ep,
                                                 ushort* __restrict__ Mp) {
    __shared__ ushort As[2 * TILE_E];
    __shared__ ushort Bs[2 * TILE_E];
    const int by = blockIdx.y;
    const int n0 = blockIdx.x * 64;
    if (by < 32)
        gemm_core<true>(Ebf + (size_t)by * 64 * KDIM, WeT,
                        (void*)(Ep + (size_t)by * 64 * HDIM), HDIM, 1.0f, As, Bs, 0, n0);
    else
        gemm_core<true>(Mbf + (size_t)(by - 32) * 64 * KDIM, WmT,
                        (void*)(Mp + (size_t)(by - 32) * 64 * HDIM), HDIM,
                        0.04419417382415922f, As, Bs, 0, n0);
}

// ---- logits[b] = Mp[b] @ Ep[b]^T ----------------------------------------------
__global__ __launch_bounds__(256) void gemm_lg(const ushort* __restrict__ Mp,
                                               const ushort* __restrict__ Ep,
                                               float* __restrict__ Lg) {
    __shared__ ushort As[2 * TILE_E];
    __shared__ ushort Bs[2 * TILE_E];
    const size_t b = blockIdx.z;
    gemm_core<false>(Mp + b * LEN_M * KDIM, Ep + b * LEN_E * KDIM,
                     (void*)(Lg + b * LEN_M * LEN_E), LEN_E, 1.0f,
                     As, Bs, blockIdx.y * 64, blockIdx.x * 64);
}

// ---- fused: dual softmax + zero + scatter + stream one chunk ------------------
// grid (c fast, bm slow): consecutive blocks write consecutive 16 KB chunks.
// All global loads hoisted above the LDS-zero loop (latency hidden under it).
__global__ __launch_bounds__(256) void softmax_distribute(const float* __restrict__ Lg,
                                                          const float* __restrict__ bq,
                                                          const float* __restrict__ bc,
                                                          const float* __restrict__ lam_,
                                                          const int* __restrict__ idx,
                                                          float* __restrict__ out) {
    __shared__ float buf[CHUNK];
    __shared__ float red[4][4];
    const int c  = blockIdx.x;          // chunk 0..7  (fast dim)
    const int bm = blockIdx.y;          // row 0..1023
    const int b  = bm >> 8;
    const int t  = threadIdx.x;
    const int lane = t & 63, wv = t >> 6;
    const int lo = c * CHUNK;
    const int e0 = t, e1 = t + 256;

    // issue ALL global loads first; latency hides under the LDS zeroing
    const int v0 = idx[b * LEN_E + e0] - lo;
    const int v1 = idx[b * LEN_E + e1] - lo;
    const float lam = lam_[bm];
    const float L0  = Lg[(size_t)bm * LEN_E + e0];
    const float L1  = Lg[(size_t)bm * LEN_E + e1];
    const float bq0 = bq[b * LEN_E + e0], bq1 = bq[b * LEN_E + e1];
    const float bc0 = bc[b * LEN_E + e0], bc1 = bc[b * LEN_E + e1];

    // zero the chunk while loads are in flight
    for (int i = t; i < CHUNK / 4; i += 256)
        ((f32x4*)buf)[i] = (f32x4){0.f, 0.f, 0.f, 0.f};

    const float xq0 = L0 + bq0, xq1 = L1 + bq1;
    const float xc0 = L0 + bc0, xc1 = L1 + bc1;

    float mq = fmaxf(xq0, xq1), mc = fmaxf(xc0, xc1);
#pragma unroll
    for (int o = 32; o; o >>= 1) {
        mq = fmaxf(mq, __shfl_xor(mq, o));
        mc = fmaxf(mc, __shfl_xor(mc, o));
    }
    if (lane == 0) { red[0][wv] = mq; red[1][wv] = mc; }
    __syncthreads();                              // also covers buf zeroing
    mq = fmaxf(fmaxf(red[0][0], red[0][1]), fmaxf(red[0][2], red[0][3]));
    mc = fmaxf(fmaxf(red[1][0], red[1][1]), fmaxf(red[1][2], red[1][3]));

    const float pq0 = expf(xq0 - mq), pq1 = expf(xq1 - mq);
    const float pc0 = expf(xc0 - mc), pc1 = expf(xc1 - mc);
    float sq = pq0 + pq1, sc = pc0 + pc1;
#pragma unroll
    for (int o = 32; o; o >>= 1) {
        sq += __shfl_xor(sq, o);
        sc += __shfl_xor(sc, o);
    }
    if (lane == 0) { red[2][wv] = sq; red[3][wv] = sc; }
    __syncthreads();
    sq = red[2][0] + red[2][1] + red[2][2] + red[2][3];
    sc = red[3][0] + red[3][1] + red[3][2] + red[3][3];

    const float val0 = lam * (pq0 / sq) + (1.f - lam) * (pc0 / sc);
    const float val1 = lam * (pq1 / sq) + (1.f - lam) * (pc1 / sc);

    // scatter (LDS atomics resolve duplicate token ids within the chunk)
    if ((unsigned)v0 < (unsigned)CHUNK) atomicAdd(&buf[v0], val0);
    if ((unsigned)v1 < (unsigned)CHUNK) atomicAdd(&buf[v1], val1);
    __syncthreads();

    // stream the chunk to global (nontemporal: write-once, bypass L2)
    f32x4* __restrict__ dst = (f32x4*)(out + (size_t)bm * VOCAB + lo);
    for (int i = t; i < CHUNK / 4; i += 256)
        __builtin_nontemporal_store(((const f32x4*)buf)[i], dst + i);
}

extern "C" void kernel_launch(void* const* d_in, const int* in_sizes, int n_in,
                              void* d_out, int out_size, void* d_ws, size_t ws_size,
                              hipStream_t stream) {
    const int*   idx = (const int*)  d_in[0];
    const float* D   = (const float*)d_in[1];
    const float* Cq  = (const float*)d_in[2];
    const float* Cc  = (const float*)d_in[3];
    const float* Mm  = (const float*)d_in[4];
    const float* E   = (const float*)d_in[5];
    const float* bq  = (const float*)d_in[6];
    const float* bc  = (const float*)d_in[7];
    const float* Wl  = (const float*)d_in[8];
    const float* bl  = (const float*)d_in[9];
    const float* We  = (const float*)d_in[10];
    const float* Wm  = (const float*)d_in[11];
    float* out = (float*)d_out;

    // workspace (16B aligned), ~9 MB
    char* w = (char*)d_ws;
    ushort* Mbf = (ushort*)w;  w += (size_t)1024 * 512 * 2;
    ushort* Ebf = (ushort*)w;  w += (size_t)2048 * 512 * 2;
    ushort* WeT = (ushort*)w;  w += (size_t)512 * 512 * 2;
    ushort* WmT = (ushort*)w;  w += (size_t)512 * 512 * 2;
    ushort* Ep  = (ushort*)w;  w += (size_t)2048 * 512 * 2;
    ushort* Mp  = (ushort*)w;  w += (size_t)1024 * 512 * 2;
    float*  Lg  = (float*)w;   w += (size_t)1024 * 512 * 4;
    float*  lam = (float*)w;

    // 1) fp32 -> bf16 (M, E elementwise; We, Wm transposed; lambda rows)
    convert_tr<<<1920, 256, 0, stream>>>(Mm, E, We, Wm, D, Cq, Cc, Wl, bl,
                                         Mbf, Ebf, WeT, WmT, lam);
    // 2) Ep = E @ We  and  Mp = H^-0.5 * (M @ Wm)   -- 384 blocks
    gemm_epmp<<<dim3(8, 48), 256, 0, stream>>>(Ebf, Mbf, WeT, WmT, Ep, Mp);
    // 3) logits[b] = Mp[b] @ Ep[b]^T                -- 128 blocks
    gemm_lg<<<dim3(8, 4, BSZ), 256, 0, stream>>>(Mp, Ep, Lg);
    // 4) fused dual softmax + zero + scatter + stream -- 8192 blocks, c-fast grid
    softmax_distribute<<<dim3(VOCAB / CHUNK, BSZ * LEN_M), 256, 0, stream>>>(
        Lg, bq, bc, lam, idx, out);
}

// Round 12
// 45.440 us; speedup vs baseline: 1.0619x; 1.0619x over previous
//
#include <hip/hip_runtime.h>
#include <math.h>

#define BSZ 4
#define LEN_M 256
#define LEN_E 512
#define HDIM 512
#define KDIM 512
#define VOCAB 32000
#define CHUNK 4000     // 16 KB LDS -> 8 blocks/CU (thread-capped), full occupancy

typedef __attribute__((ext_vector_type(8))) short bf16x8;
typedef __attribute__((ext_vector_type(4))) float f32x4;

__device__ inline ushort f2bf(float x) {
    union { float f; unsigned u; } v; v.f = x;
    unsigned r = v.u + 0x7FFFu + ((v.u >> 16) & 1u);   // RNE
    return (ushort)(r >> 16);
}

// ---- bf16 A[M][K] @ B[N][K]^T core: 64x64 tile, 4 waves, 16x16x32 MFMA -------
// LROW=72: 16B-aligned b128 ops, lanes spread across disjoint 4-bank groups.
// Single-buffered: R11 A/B showed explicit dbuf is neutral-to-negative here
// (compiler + 1.5-3 blocks/CU TLP already hide the staging latency).
#define LROW 72
template<bool OUT_BF16>
__device__ __forceinline__ void gemm_core(const ushort* __restrict__ Ab,
                                          const ushort* __restrict__ Bb,
                                          void* __restrict__ Cb, int N, float scale,
                                          ushort* As, ushort* Bs, int m0, int n0) {
    const int t = threadIdx.x;
    const int wid = t >> 6, lane = t & 63;
    const int wr = wid >> 1, wc = wid & 1;
    const int lrow = lane & 15, lk = (lane >> 4) * 8;
    const int r0 = t >> 3;
    const int c8 = (t & 7) * 8;

    bf16x8 pa0, pa1, pb0, pb1;
    f32x4 acc[2][2] = {};

    pa0 = *(const bf16x8*)&Ab[(size_t)(m0 + r0)      * KDIM + c8];
    pa1 = *(const bf16x8*)&Ab[(size_t)(m0 + r0 + 32) * KDIM + c8];
    pb0 = *(const bf16x8*)&Bb[(size_t)(n0 + r0)      * KDIM + c8];
    pb1 = *(const bf16x8*)&Bb[(size_t)(n0 + r0 + 32) * KDIM + c8];
    *(bf16x8*)&As[(r0)      * LROW + c8] = pa0;
    *(bf16x8*)&As[(r0 + 32) * LROW + c8] = pa1;
    *(bf16x8*)&Bs[(r0)      * LROW + c8] = pb0;
    *(bf16x8*)&Bs[(r0 + 32) * LROW + c8] = pb1;
    __syncthreads();

    for (int kt = 0; kt < KDIM / 64; ++kt) {
        if (kt + 1 < KDIM / 64) {
            const int k0 = (kt + 1) * 64;
            pa0 = *(const bf16x8*)&Ab[(size_t)(m0 + r0)      * KDIM + k0 + c8];
            pa1 = *(const bf16x8*)&Ab[(size_t)(m0 + r0 + 32) * KDIM + k0 + c8];
            pb0 = *(const bf16x8*)&Bb[(size_t)(n0 + r0)      * KDIM + k0 + c8];
            pb1 = *(const bf16x8*)&Bb[(size_t)(n0 + r0 + 32) * KDIM + k0 + c8];
        }
#pragma unroll
        for (int ks = 0; ks < 2; ++ks) {
            bf16x8 af[2], bfr[2];
#pragma unroll
            for (int i = 0; i < 2; ++i)
                af[i]  = *(const bf16x8*)&As[(wr * 32 + i * 16 + lrow) * LROW + ks * 32 + lk];
#pragma unroll
            for (int j = 0; j < 2; ++j)
                bfr[j] = *(const bf16x8*)&Bs[(wc * 32 + j * 16 + lrow) * LROW + ks * 32 + lk];
#pragma unroll
            for (int i = 0; i < 2; ++i)
#pragma unroll
                for (int j = 0; j < 2; ++j)
                    acc[i][j] = __builtin_amdgcn_mfma_f32_16x16x32_bf16(af[i], bfr[j], acc[i][j], 0, 0, 0);
        }
        __syncthreads();
        if (kt + 1 < KDIM / 64) {
            *(bf16x8*)&As[(r0)      * LROW + c8] = pa0;
            *(bf16x8*)&As[(r0 + 32) * LROW + c8] = pa1;
            *(bf16x8*)&Bs[(r0)      * LROW + c8] = pb0;
            *(bf16x8*)&Bs[(r0 + 32) * LROW + c8] = pb1;
            __syncthreads();
        }
    }

    // C/D layout (m89): col = lane&15, row = (lane>>4)*4 + reg
    const int crow = m0 + wr * 32 + (lane >> 4) * 4;
    const int ccol = n0 + wc * 32 + lrow;
#pragma unroll
    for (int i = 0; i < 2; ++i)
#pragma unroll
        for (int j = 0; j < 2; ++j)
#pragma unroll
            for (int r = 0; r < 4; ++r) {
                const size_t o = (size_t)(crow + i * 16 + r) * N + ccol + j * 16;
                const float v = acc[i][j][r] * scale;
                if (OUT_BF16) ((ushort*)Cb)[o] = f2bf(v);
                else          ((float*)Cb)[o]  = v;
            }
}

// ---- convert M,E -> bf16; We,Wm -> bf16 transposed; lambda per row -----------
// blocks 0..1535: elementwise | 1536..1663: transposes | 1664..1919: lambda
__global__ __launch_bounds__(256) void convert_tr(const float* __restrict__ M_,
                                                  const float* __restrict__ E_,
                                                  const float* __restrict__ We_,
                                                  const float* __restrict__ Wm_,
                                                  const float* __restrict__ D,
                                                  const float* __restrict__ Cq,
                                                  const float* __restrict__ Cc,
                                                  const float* __restrict__ Wl,
                                                  const float* __restrict__ bl,
                                                  ushort* __restrict__ Mbf,
                                                  ushort* __restrict__ Ebf,
                                                  ushort* __restrict__ WeT,
                                                  ushort* __restrict__ WmT,
                                                  float* __restrict__ lam) {
    __shared__ ushort Ts[64][68];
    const int blk = blockIdx.x;
    if (blk < 1536) {
        const int i4 = blk * 256 + threadIdx.x;
        const float* src; ushort* dst; int off;
        if (i4 < 131072) { src = M_; dst = Mbf; off = 0; }
        else             { src = E_; dst = Ebf; off = 131072; }
        const int j = i4 - off;
        const float4 v = ((const float4*)src)[j];
        ushort4 o; o.x = f2bf(v.x); o.y = f2bf(v.y); o.z = f2bf(v.z); o.w = f2bf(v.w);
        ((ushort4*)dst)[j] = o;
    } else if (blk < 1664) {
        const int ti  = blk - 1536;
        const int mat = ti >> 6;
        const int tt  = ti & 63;
        const int kt  = tt >> 3, nt = tt & 7;
        const float* W = mat ? Wm_ : We_;
        ushort* WT     = mat ? WmT : WeT;
        const int r = threadIdx.x >> 4, c4 = (threadIdx.x & 15) * 4;
#pragma unroll
        for (int p = 0; p < 4; ++p) {
            const int row = r + p * 16;
            const float4 v = *(const float4*)&W[(size_t)(kt * 64 + row) * HDIM + nt * 64 + c4];
            Ts[row][c4 + 0] = f2bf(v.x); Ts[row][c4 + 1] = f2bf(v.y);
            Ts[row][c4 + 2] = f2bf(v.z); Ts[row][c4 + 3] = f2bf(v.w);
        }
        __syncthreads();
#pragma unroll
        for (int p = 0; p < 4; ++p) {
            const int row = r + p * 16;
            ushort4 o;
            o.x = Ts[c4 + 0][row]; o.y = Ts[c4 + 1][row];
            o.z = Ts[c4 + 2][row]; o.w = Ts[c4 + 3][row];
            *(ushort4*)&WT[(size_t)(nt * 64 + row) * HDIM + kt * 64 + c4] = o;
        }
    } else {
        // lambda: one wave per row, 4 rows per block
        const int lane = threadIdx.x & 63, wv = threadIdx.x >> 6;
        const int bm = (blk - 1664) * 4 + wv;          // 0..1023
        const size_t rb = (size_t)bm * HDIM;
        float s = 0.f;
#pragma unroll
        for (int h = 0; h < HDIM; h += 64) {
            const int e = h + lane;
            s += D[rb + e] * Wl[e] + Cq[rb + e] * Wl[HDIM + e] + Cc[rb + e] * Wl[2 * HDIM + e];
        }
#pragma unroll
        for (int o = 32; o; o >>= 1) s += __shfl_xor(s, o);
        if (lane == 0) lam[bm] = 1.f / (1.f + expf(-(s + bl[0])));
    }
}

// ---- Ep = E @ We and Mp = s * (M @ Wm) in ONE launch --------------------------
__global__ __launch_bounds__(256) void gemm_epmp(const ushort* __restrict__ Ebf,
                                                 const ushort* __restrict__ Mbf,
                                                 const ushort* __restrict__ WeT,
                                                 const ushort* __restrict__ WmT,
                                                 ushort* __restrict__ Ep,
                                                 ushort* __restrict__ Mp) {
    __shared__ ushort As[64 * LROW];
    __shared__ ushort Bs[64 * LROW];
    const int by = blockIdx.y;
    const int n0 = blockIdx.x * 64;
    if (by < 32)
        gemm_core<true>(Ebf + (size_t)by * 64 * KDIM, WeT,
                        (void*)(Ep + (size_t)by * 64 * HDIM), HDIM, 1.0f, As, Bs, 0, n0);
    else
        gemm_core<true>(Mbf + (size_t)(by - 32) * 64 * KDIM, WmT,
                        (void*)(Mp + (size_t)(by - 32) * 64 * HDIM), HDIM,
                        0.04419417382415922f, As, Bs, 0, n0);
}

// ---- logits[b] = Mp[b] @ Ep[b]^T ----------------------------------------------
__global__ __launch_bounds__(256) void gemm_lg(const ushort* __restrict__ Mp,
                                               const ushort* __restrict__ Ep,
                                               float* __restrict__ Lg) {
    __shared__ ushort As[64 * LROW];
    __shared__ ushort Bs[64 * LROW];
    const size_t b = blockIdx.z;
    gemm_core<false>(Mp + b * LEN_M * KDIM, Ep + b * LEN_E * KDIM,
                     (void*)(Lg + b * LEN_M * LEN_E), LEN_E, 1.0f,
                     As, Bs, blockIdx.y * 64, blockIdx.x * 64);
}

// ---- fused: dual softmax + zero + scatter + stream one chunk ------------------
// grid (c fast, bm slow): consecutive blocks write consecutive 16 KB chunks.
// PLAIN stores (not nontemporal): the 131 MB output fits in the 256 MB L3 —
// let dirty lines drain to HBM in the background instead of committing inside
// the kernel's critical path.
__global__ __launch_bounds__(256) void softmax_distribute(const float* __restrict__ Lg,
                                                          const float* __restrict__ bq,
                                                          const float* __restrict__ bc,
                                                          const float* __restrict__ lam_,
                                                          const int* __restrict__ idx,
                                                          float* __restrict__ out) {
    __shared__ float buf[CHUNK];
    __shared__ float red[4][4];
    const int c  = blockIdx.x;          // chunk 0..7  (fast dim)
    const int bm = blockIdx.y;          // row 0..1023
    const int b  = bm >> 8;
    const int t  = threadIdx.x;
    const int lane = t & 63, wv = t >> 6;
    const int lo = c * CHUNK;
    const int e0 = t, e1 = t + 256;

    // early loads (L2-resident)
    const int v0 = idx[b * LEN_E + e0] - lo;
    const int v1 = idx[b * LEN_E + e1] - lo;
    const float lam = lam_[bm];

    // zero the chunk while the prelude's loads are in flight
    for (int i = t; i < CHUNK / 4; i += 256)
        ((f32x4*)buf)[i] = (f32x4){0.f, 0.f, 0.f, 0.f};

    const float L0 = Lg[(size_t)bm * LEN_E + e0];
    const float L1 = Lg[(size_t)bm * LEN_E + e1];
    const float xq0 = L0 + bq[b * LEN_E + e0], xq1 = L1 + bq[b * LEN_E + e1];
    const float xc0 = L0 + bc[b * LEN_E + e0], xc1 = L1 + bc[b * LEN_E + e1];

    float mq = fmaxf(xq0, xq1), mc = fmaxf(xc0, xc1);
#pragma unroll
    for (int o = 32; o; o >>= 1) {
        mq = fmaxf(mq, __shfl_xor(mq, o));
        mc = fmaxf(mc, __shfl_xor(mc, o));
    }
    if (lane == 0) { red[0][wv] = mq; red[1][wv] = mc; }
    __syncthreads();                              // also covers buf zeroing
    mq = fmaxf(fmaxf(red[0][0], red[0][1]), fmaxf(red[0][2], red[0][3]));
    mc = fmaxf(fmaxf(red[1][0], red[1][1]), fmaxf(red[1][2], red[1][3]));

    const float pq0 = expf(xq0 - mq), pq1 = expf(xq1 - mq);
    const float pc0 = expf(xc0 - mc), pc1 = expf(xc1 - mc);
    float sq = pq0 + pq1, sc = pc0 + pc1;
#pragma unroll
    for (int o = 32; o; o >>= 1) {
        sq += __shfl_xor(sq, o);
        sc += __shfl_xor(sc, o);
    }
    if (lane == 0) { red[2][wv] = sq; red[3][wv] = sc; }
    __syncthreads();
    sq = red[2][0] + red[2][1] + red[2][2] + red[2][3];
    sc = red[3][0] + red[3][1] + red[3][2] + red[3][3];

    const float val0 = lam * (pq0 / sq) + (1.f - lam) * (pc0 / sc);
    const float val1 = lam * (pq1 / sq) + (1.f - lam) * (pc1 / sc);

    // scatter (LDS atomics resolve duplicate token ids within the chunk)
    if ((unsigned)v0 < (unsigned)CHUNK) atomicAdd(&buf[v0], val0);
    if ((unsigned)v1 < (unsigned)CHUNK) atomicAdd(&buf[v1], val1);
    __syncthreads();

    // stream the chunk to global (plain stores -> L2/L3, lazy HBM drain)
    f32x4* __restrict__ dst = (f32x4*)(out + (size_t)bm * VOCAB + lo);
    for (int i = t; i < CHUNK / 4; i += 256)
        dst[i] = ((const f32x4*)buf)[i];
}

extern "C" void kernel_launch(void* const* d_in, const int* in_sizes, int n_in,
                              void* d_out, int out_size, void* d_ws, size_t ws_size,
                              hipStream_t stream) {
    const int*   idx = (const int*)  d_in[0];
    const float* D   = (const float*)d_in[1];
    const float* Cq  = (const float*)d_in[2];
    const float* Cc  = (const float*)d_in[3];
    const float* Mm  = (const float*)d_in[4];
    const float* E   = (const float*)d_in[5];
    const float* bq  = (const float*)d_in[6];
    const float* bc  = (const float*)d_in[7];
    const float* Wl  = (const float*)d_in[8];
    const float* bl  = (const float*)d_in[9];
    const float* We  = (const float*)d_in[10];
    const float* Wm  = (const float*)d_in[11];
    float* out = (float*)d_out;

    // workspace (16B aligned), ~9 MB
    char* w = (char*)d_ws;
    ushort* Mbf = (ushort*)w;  w += (size_t)1024 * 512 * 2;
    ushort* Ebf = (ushort*)w;  w += (size_t)2048 * 512 * 2;
    ushort* WeT = (ushort*)w;  w += (size_t)512 * 512 * 2;
    ushort* WmT = (ushort*)w;  w += (size_t)512 * 512 * 2;
    ushort* Ep  = (ushort*)w;  w += (size_t)2048 * 512 * 2;
    ushort* Mp  = (ushort*)w;  w += (size_t)1024 * 512 * 2;
    float*  Lg  = (float*)w;   w += (size_t)1024 * 512 * 4;
    float*  lam = (float*)w;

    // 1) fp32 -> bf16 (M, E elementwise; We, Wm transposed; lambda rows)
    convert_tr<<<1920, 256, 0, stream>>>(Mm, E, We, Wm, D, Cq, Cc, Wl, bl,
                                         Mbf, Ebf, WeT, WmT, lam);
    // 2) Ep = E @ We  and  Mp = H^-0.5 * (M @ Wm)   -- 384 blocks
    gemm_epmp<<<dim3(8, 48), 256, 0, stream>>>(Ebf, Mbf, WeT, WmT, Ep, Mp);
    // 3) logits[b] = Mp[b] @ Ep[b]^T                -- 128 blocks
    gemm_lg<<<dim3(8, 4, BSZ), 256, 0, stream>>>(Mp, Ep, Lg);
    // 4) fused dual softmax + zero + scatter + stream -- 8192 blocks, c-fast grid
    softmax_distribute<<<dim3(VOCAB / CHUNK, BSZ * LEN_M), 256, 0, stream>>>(
        Lg, bq, bc, lam, idx, out);
}